// Round 7
// baseline (259.942 us; speedup 1.0000x reference)
//
#include <hip/hip_runtime.h>

typedef __bf16 bf16x8 __attribute__((ext_vector_type(8)));
typedef float  f32x4  __attribute__((ext_vector_type(4)));
typedef float  f32x16 __attribute__((ext_vector_type(16)));
typedef unsigned int uint;

__device__ inline unsigned short f2bf(float f) {
  union { float f; unsigned int u; } v; v.f = f;
  unsigned int u = v.u;
  unsigned int r = u + 0x7FFF + ((u >> 16) & 1);   // RNE
  return (unsigned short)(r >> 16);
}

// pack two floats to packed bf16x2 with round-half-up (err <= 0.5 ulp)
__device__ inline uint pack_bf16_rhu(float a, float b) {
  uint ua = __builtin_bit_cast(uint, a) + 0x8000u;
  uint ub = __builtin_bit_cast(uint, b) + 0x8000u;
  return __builtin_amdgcn_perm(ub, ua, 0x07060302u);
}

__device__ inline void load_lds16(const unsigned short* g, unsigned short* l) {
  __builtin_amdgcn_global_load_lds(
      (const __attribute__((address_space(1))) uint*)(g),
      (__attribute__((address_space(3))) uint*)(l), 16, 0, 0);
}

// ---------------------------------------------------------------- fused convert
__device__ inline void cvt4(const float* in, unsigned short* out) {
  float4 f = *reinterpret_cast<const float4*>(in);
  ushort4 o;
  o.x = f2bf(f.x); o.y = f2bf(f.y); o.z = f2bf(f.z); o.w = f2bf(f.w);
  *reinterpret_cast<ushort4*>(out) = o;
}

__global__ void cvt_all(const float* __restrict__ x, const float* __restrict__ w_in,
                        const float* __restrict__ w_out,
                        unsigned short* __restrict__ x_bf,
                        unsigned short* __restrict__ w_in_bf,
                        unsigned short* __restrict__ w_out_bf) {
  const int n1 = 8192 * 1024, n2 = 3072 * 1024;
  int i = (blockIdx.x * blockDim.x + threadIdx.x) * 4;
  if (i < n1)            cvt4(x + i, x_bf + i);
  else if (i < n1 + n2)  cvt4(w_in + (i - n1), w_in_bf + (i - n1));
  else                   cvt4(w_out + (i - n1 - n2), w_out_bf + (i - n1 - n2));
}

// ---------------------------------------------------------------- GEMM  C = A * B^T + bias
// m97 structure + XOR-swizzled LDS (verified 0 conflicts R4). Unchanged from R6.
template<bool OUT_BF16, bool VSPLIT>
__global__ __launch_bounds__(256) void gemm_bt128(
    const unsigned short* __restrict__ A,
    const unsigned short* __restrict__ B,
    const float* __restrict__ bias,
    void* __restrict__ Cout,
    unsigned short* __restrict__ vt,
    int M, int N, int K, int ldc, float scale, int ncut)
{
  __shared__ __attribute__((aligned(16))) unsigned short As[128 * 64];
  __shared__ __attribute__((aligned(16))) unsigned short Bs[128 * 64];

  const int t    = threadIdx.x;
  const int wave = t >> 6, lane = t & 63;
  const int l16  = lane & 15, quad = lane >> 4;
  const int wr = wave >> 1, wc = wave & 1;
  const int m0 = blockIdx.y * 128, n0 = blockIdx.x * 128;
  const int l8 = l16 & 7;

  f32x4 acc[4][4] = {};

  for (int k0 = 0; k0 < K; k0 += 64) {
#pragma unroll
    for (int i = 0; i < 4; ++i) {
      int chunk = i * 256 + t;
      int row = chunk >> 3, cb = chunk & 7;
      int gcb = cb ^ (row & 7);
      load_lds16(A + (size_t)(m0 + row) * K + k0 + gcb * 8, As + chunk * 8);
    }
#pragma unroll
    for (int i = 0; i < 4; ++i) {
      int chunk = i * 256 + t;
      int row = chunk >> 3, cb = chunk & 7;
      int gcb = cb ^ (row & 7);
      load_lds16(B + (size_t)(n0 + row) * K + k0 + gcb * 8, Bs + chunk * 8);
    }
    __syncthreads();
#pragma unroll
    for (int ks = 0; ks < 2; ++ks) {
      bf16x8 af[4], bfr[4];
#pragma unroll
      for (int mt = 0; mt < 4; ++mt)
        af[mt] = *(const bf16x8*)(As + (wr * 64 + mt * 16 + l16) * 64 +
                                  (((ks * 4 + quad) ^ l8) << 3));
#pragma unroll
      for (int nt = 0; nt < 4; ++nt)
        bfr[nt] = *(const bf16x8*)(Bs + (wc * 64 + nt * 16 + l16) * 64 +
                                   (((ks * 4 + quad) ^ l8) << 3));
#pragma unroll
      for (int mt = 0; mt < 4; ++mt)
#pragma unroll
        for (int nt = 0; nt < 4; ++nt)
          acc[mt][nt] = __builtin_amdgcn_mfma_f32_16x16x32_bf16(af[mt], bfr[nt], acc[mt][nt], 0, 0, 0);
    }
    __syncthreads();
  }

#pragma unroll
  for (int nt = 0; nt < 4; ++nt) {
    int col = n0 + wc * 64 + nt * 16 + l16;
    float bv = bias[col];
    float mlt = (col < ncut) ? scale : 1.0f;
#pragma unroll
    for (int mt = 0; mt < 4; ++mt) {
      int row0 = m0 + wr * 64 + mt * 16 + quad * 4;
      float v0 = (acc[mt][nt][0] + bv) * mlt;
      float v1 = (acc[mt][nt][1] + bv) * mlt;
      float v2 = (acc[mt][nt][2] + bv) * mlt;
      float v3 = (acc[mt][nt][3] + bv) * mlt;
      if (VSPLIT && col >= 2048) {
        int d = col - 2048, h = d >> 6, dd = d & 63;
        int bb = row0 >> 11, s = row0 & 2047;
        uint2 w;
        w.x = pack_bf16_rhu(v0, v1);
        w.y = pack_bf16_rhu(v2, v3);
        *(uint2*)(vt + ((size_t)((bb * 16 + h) * 64 + dd) * 2048 + s)) = w;
      } else {
#pragma unroll
        for (int r = 0; r < 4; ++r) {
          float v = (r == 0) ? v0 : (r == 1) ? v1 : (r == 2) ? v2 : v3;
          if (OUT_BF16)
            ((unsigned short*)Cout)[(size_t)(row0 + r) * ldc + col] = f2bf(v);
          else
            ((float*)Cout)[(size_t)(row0 + r) * ldc + col] = v;
        }
      }
    }
  }
}

// ---------------------------------------------------------------- flash attention (32x32 MFMA)
// 64-row Q-tile, grid 2048 heavy-first. Per 64kv iter, 3-phase:
//   S-phase: wave (qh,kh) computes S^T 32x32 tile = K(LDS) x Q^T(regs); exp in-lane;
//            P packed to LDS tile P2[q][kv] (granule-swizzled).
//   PV-phase: wave (dh=kh, qh) computes O^T 32x32 (full kv) = V^T(LDS) x P^T(LDS).
// MFMA 32x32x16: A[m=lane&31][k=(lane>>5)*8+j]; B[k=(lane>>5)*8+j][n=lane&31];
// C/D: col=lane&31, row=(reg&3)+8*(reg>>2)+4*(lane>>5)  [m74/m101 verified].
__global__ __launch_bounds__(256) void attn(
    const unsigned short* __restrict__ qkv2,   // (B*S) x 2048 : Q|K
    const unsigned short* __restrict__ vt,     // [bh][d][s]
    unsigned short* __restrict__ y,
    const int* __restrict__ flag)
{
  __shared__ __attribute__((aligned(16))) unsigned short P2[64 * 64];  // P^T as [q][kv]; O as [q][d] in epilogue
  __shared__ __attribute__((aligned(16))) unsigned short Ks[64 * 64];  // [kv][d]
  __shared__ __attribute__((aligned(16))) unsigned short VtF[64 * 64]; // [d][kv]
  __shared__ float Lbuf[2][2][32];

  const int t    = threadIdx.x;
  const int wave = t >> 6, lane = t & 63;
  const int l32  = lane & 31, hi = lane >> 5;
  const int qh = wave & 1, kh = wave >> 1;   // kh doubles as dh in PV phase
  const int idx = blockIdx.x;
  const int bh  = idx & 63;
  const int qt  = 31 - (idx >> 6);           // heavy first
  const int b = bh >> 4, h = bh & 15;
  const int causal = flag[0];
  const int q0 = qt * 64;
  const int swz = l32 & 7;

  const unsigned short* Qg  = qkv2 + (size_t)b * 2048 * 2048 + h * 64;
  const unsigned short* Kg  = Qg + 1024;
  const unsigned short* Vtg = vt + (size_t)bh * 64 * 2048;

  const int qrow_lds = qh * 32 + l32;        // q row this lane owns in P2
  const int q_glob   = q0 + qrow_lds;

  // Q B-fragments direct from global (hoisted for whole kernel)
  bf16x8 qf[4];
  {
    const unsigned short* qr = Qg + (size_t)q_glob * 2048 + hi * 8;
    qf[0] = *(const bf16x8*)(qr);
    qf[1] = *(const bf16x8*)(qr + 16);
    qf[2] = *(const bf16x8*)(qr + 32);
    qf[3] = *(const bf16x8*)(qr + 48);
  }

  // staging coords (R6 pattern, verified)
  const int sr = t >> 2, sg = (t & 3) * 2;
  const int slot0 = sr * 64 + ((sg ^ (sr & 7)) << 3);
  const int slot1 = sr * 64 + (((sg + 1) ^ (sr & 7)) << 3);
  const int vb = t & 3;
  const int vslot0 = sr * 64 + ((vb ^ (sr & 7)) << 3);
  const int vslot1 = sr * 64 + (((vb + 4) ^ (sr & 7)) << 3);
  const unsigned short* vrow = Vtg + (size_t)sr * 2048;

  f32x16 ot = {};
  float l_lane = 0.f;
  const int jmax = causal ? qt : 31;

  // prefetch j = 0
  uint4 kreg0, kreg1, vreg0, vreg1;
  {
    const unsigned short* src = Kg + (size_t)sr * 2048 + sg * 8;
    kreg0 = *(const uint4*)src;
    kreg1 = *(const uint4*)(src + 8);
    vreg0 = *(const uint4*)(vrow + vb * 8);
    vreg1 = *(const uint4*)(vrow + vb * 8 + 32);
  }

  for (int j = 0; j <= jmax; ++j) {
    *(uint4*)(Ks + slot0)   = kreg0;
    *(uint4*)(Ks + slot1)   = kreg1;
    *(uint4*)(VtF + vslot0) = vreg0;
    *(uint4*)(VtF + vslot1) = vreg1;
    __syncthreads();                         // bar1: staging visible

    if (j < jmax) {
      const int kvn = (j + 1) * 64;
      const unsigned short* src = Kg + (size_t)(kvn + sr) * 2048 + sg * 8;
      kreg0 = *(const uint4*)src;
      kreg1 = *(const uint4*)(src + 8);
      vreg0 = *(const uint4*)(vrow + kvn + vb * 8);
      vreg1 = *(const uint4*)(vrow + kvn + vb * 8 + 32);
    }

    // ---- S-phase: S^T(32kv x 32q) = K x Q^T
    f32x16 st = {};
    {
      const unsigned short* kbase = Ks + (kh * 32 + l32) * 64;
#pragma unroll
      for (int dstep = 0; dstep < 4; ++dstep) {
        bf16x8 kf = *(const bf16x8*)(kbase + (((dstep * 2 + hi) ^ swz) << 3));
        st = __builtin_amdgcn_mfma_f32_32x32x16_bf16(kf, qf[dstep], st, 0, 0, 0);
      }
    }

    // exp (scores pre-scaled by 0.125*log2e in GEMM) + causal mask + pack P
    const bool diag = (causal != 0) && (j == qt);
    const int kv0 = j * 64;
#pragma unroll
    for (int rr = 0; rr < 4; ++rr) {
      float p[4];
#pragma unroll
      for (int r = 0; r < 4; ++r) {
        float pv = __builtin_amdgcn_exp2f(st[rr * 4 + r]);
        if (diag) {
          int kv = kv0 + kh * 32 + rr * 8 + hi * 4 + r;
          if (kv > q_glob) pv = 0.f;
        }
        p[r] = pv;
      }
      l_lane += (p[0] + p[1]) + (p[2] + p[3]);
      uint2 w;
      w.x = pack_bf16_rhu(p[0], p[1]);
      w.y = pack_bf16_rhu(p[2], p[3]);
      int G = kh * 4 + rr;                   // absolute kv granule
      *(uint2*)(P2 + qrow_lds * 64 + (((G ^ swz) << 3) + hi * 4)) = w;
    }
    __syncthreads();                         // bar2: P2 visible

    // ---- PV-phase: O^T(32d x 32q) += V^T x P^T over full 64 kv
    {
      const unsigned short* vbase = VtF + (kh * 32 + l32) * 64;   // kh = dh
      const unsigned short* pbase = P2 + qrow_lds * 64;
#pragma unroll
      for (int kstep = 0; kstep < 4; ++kstep) {
        int G = kstep * 2 + hi;
        bf16x8 vf = *(const bf16x8*)(vbase + (((G ^ swz) << 3)));
        bf16x8 pf = *(const bf16x8*)(pbase + (((G ^ swz) << 3)));
        ot = __builtin_amdgcn_mfma_f32_32x32x16_bf16(vf, pf, ot, 0, 0, 0);
      }
    }
    __syncthreads();                         // bar3: Ks/VtF/P2 free for next iter
  }

  // ---- l: in-wave hi-halves, then cross-wave over kh via LDS
  l_lane += __shfl_xor(l_lane, 32);
  Lbuf[qh][kh][l32] = l_lane;
  __syncthreads();
  const float inv = 1.f / (Lbuf[qh][0][l32] + Lbuf[qh][1][l32]);

  // ---- normalize + pack O^T into P2 as [q][d] (kh = dh)
#pragma unroll
  for (int rr = 0; rr < 4; ++rr) {
    uint2 w;
    w.x = pack_bf16_rhu(ot[rr * 4 + 0] * inv, ot[rr * 4 + 1] * inv);
    w.y = pack_bf16_rhu(ot[rr * 4 + 2] * inv, ot[rr * 4 + 3] * inv);
    int G = kh * 4 + rr;                     // d granule
    *(uint2*)(P2 + qrow_lds * 64 + (((G ^ swz) << 3) + hi * 4)) = w;
  }
  __syncthreads();
  {
    size_t base = ((size_t)b * 2048 + q0 + sr) * 1024 + h * 64 + sg * 8;
    *(uint4*)(y + base)     = *(const uint4*)(P2 + slot0);
    *(uint4*)(y + base + 8) = *(const uint4*)(P2 + slot1);
  }
}

// ---------------------------------------------------------------- launch
extern "C" void kernel_launch(void* const* d_in, const int* in_sizes, int n_in,
                              void* d_out, int out_size, void* d_ws, size_t ws_size,
                              hipStream_t stream) {
  const float* x     = (const float*)d_in[0];
  const float* w_in  = (const float*)d_in[1];
  const float* b_in  = (const float*)d_in[2];
  const float* w_out = (const float*)d_in[3];
  const float* b_out = (const float*)d_in[4];
  const int*   cmask = (const int*)d_in[5];

  char* ws = (char*)d_ws;
  unsigned short* x_bf     = (unsigned short*)(ws);               // 8192x1024  (16 MB)
  unsigned short* w_in_bf  = (unsigned short*)(ws + 16777216);    // 3072x1024  (6 MB)
  unsigned short* w_out_bf = (unsigned short*)(ws + 23068672);    // 1024x1024  (2 MB)
  unsigned short* qkv2_bf  = (unsigned short*)(ws + 25165824);    // 8192x2048 Q|K (32 MB)
  unsigned short* vt_bf    = (unsigned short*)(ws + 58720256);    // 64bh x 64d x 2048s (16 MB)
  unsigned short* y_bf     = (unsigned short*)(ws + 75497472);    // 8192x1024  (16 MB)

  const int ntot = (8192 + 3072 + 1024) * 1024;
  cvt_all<<<dim3(ntot / 4 / 256), 256, 0, stream>>>(x, w_in, w_out, x_bf, w_in_bf, w_out_bf);

  // QKV = x * w_in^T + b_in ; Q cols pre-scaled; Q|K -> qkv2 row-major, V -> vt transposed
  gemm_bt128<true, true><<<dim3(24, 64), 256, 0, stream>>>(
      x_bf, w_in_bf, b_in, qkv2_bf, vt_bf, 8192, 3072, 1024, 2048,
      0.18033688011112042f, 1024);

  // flash attention -> y_bf (8192 x 1024)
  attn<<<dim3(2048), 256, 0, stream>>>(qkv2_bf, vt_bf, y_bf, cmask);

  // out = y * w_out^T + b_out -> fp32 d_out
  gemm_bt128<false, false><<<dim3(8, 64), 256, 0, stream>>>(
      y_bf, w_out_bf, b_out, d_out, nullptr, 8192, 1024, 1024, 1024, 1.0f, 0);
}